// Round 12
// baseline (2038.531 us; speedup 1.0000x reference)
//
#include <hip/hip_runtime.h>
#include <math.h>

typedef unsigned short u16;
typedef unsigned int   u32;
typedef __attribute__((ext_vector_type(8))) short bf16x8;
typedef __attribute__((ext_vector_type(4))) float f32x4;

#define DEV static __device__ __forceinline__

DEV u16 f2b(float f) {
  union { float f; u32 u; } v; v.f = f;
  u32 r = v.u + 0x7FFFu + ((v.u >> 16) & 1u);
  return (u16)(r >> 16);
}
DEV float b2f(u16 h) {
  union { u32 u; float f; } v; v.u = ((u32)h) << 16;
  return v.f;
}
DEV float gelu_f(float x) { return 0.5f * x * (1.0f + erff(x * 0.70710678118654752f)); }

DEV void gload16(const u16* g, u16* l) {
  __builtin_amdgcn_global_load_lds(
      (const __attribute__((address_space(1))) void*)g,
      (__attribute__((address_space(3))) void*)l, 16, 0, 0);
}

// ---------------- weight transpose: fp32 (K,N) -> bf16 (N,K) ----------------
__global__ void k_transpose_w(const float* __restrict__ src, u16* __restrict__ dst,
                              int K, int N) {
  long t = (long)blockIdx.x * 256 + threadIdx.x;
  if (t >= (long)K * N) return;
  int n = (int)(t / K), k = (int)(t % K);
  dst[t] = f2b(src[(long)k * N + n]);
}

// ---------------- per-window uncertainty mean (numpy pairwise order) --------
__global__ void k_scores(const float* __restrict__ unc, float* __restrict__ scores) {
  int id = blockIdx.x * 256 + threadIdx.x;
  if (id >= 8192) return;
  int b = id >> 12, win = id & 4095;
  int h0 = (win >> 6) << 3, w0 = (win & 63) << 3;
  float r[8] = {0.f,0.f,0.f,0.f,0.f,0.f,0.f,0.f};
  for (int i = 0; i < 8; ++i) {
    long base = ((long)(b * 512 + h0 + i)) * 512 + w0;
    #pragma unroll
    for (int j = 0; j < 8; ++j) r[j] += unc[base + j];
  }
  float s = ((r[0] + r[1]) + (r[2] + r[3])) + ((r[4] + r[5]) + (r[6] + r[7]));
  scores[id] = s * (1.0f / 64.0f);
}

// ---------------- top-k (1228 of 4096) per batch: bitonic, tie -> lower idx --
__global__ __launch_bounds__(1024) void k_topk(
    const float* __restrict__ scores, int* __restrict__ row2win,
    int* __restrict__ win2row, int nWF) {
  __shared__ float ls[4096];
  __shared__ int   li[4096];
  const int b = blockIdx.x;
  const int tid = threadIdx.x;
  for (int i = tid; i < 4096; i += 1024) {
    ls[i] = scores[b * 4096 + i];
    li[i] = i;
    win2row[b * 4096 + i] = -1;
  }
  __syncthreads();
  for (int k = 2; k <= 4096; k <<= 1) {
    for (int j = k >> 1; j > 0; j >>= 1) {
      for (int t = tid; t < 2048; t += 1024) {
        int i = ((t / j) * (j << 1)) + (t % j);
        int ixj = i + j;
        bool up = ((i & k) == 0);
        float sa = ls[i], sb = ls[ixj];
        int ia = li[i], ib = li[ixj];
        bool g = (sa > sb) || (sa == sb && ia < ib);
        if (g != up) { ls[i] = sb; ls[ixj] = sa; li[i] = ib; li[ixj] = ia; }
      }
      __syncthreads();
    }
  }
  for (int r = tid; r < nWF; r += 1024) {
    int win = li[r];
    row2win[b * nWF + r] = (b << 12) | win;
    win2row[b * 4096 + win] = b * nWF + r;
  }
}

// ---------------- gather selected window + LayerNorm -> xn (bf16) ----------
__global__ __launch_bounds__(256) void k_gather_ln(
    const float* __restrict__ fm, const float* __restrict__ nw,
    const float* __restrict__ nb, const int* __restrict__ row2win,
    u16* __restrict__ xn, int winStart) {
  __shared__ float sx[64 * 256];
  const int tid = threadIdx.x;
  const int rw = row2win[winStart + blockIdx.x];
  const int b = rw >> 12, win = rw & 4095;
  const int h0 = (win >> 6) << 3, w0 = (win & 63) << 3;
  {
    const int c8 = tid >> 3, h = tid & 7;
    #pragma unroll
    for (int cc = 0; cc < 8; ++cc) {
      const int c = cc * 32 + c8;
      long base = ((long)(b * 256 + c) * 512 + h0 + h) * 512 + w0;
      float4 v0 = *(const float4*)(fm + base);
      float4 v1 = *(const float4*)(fm + base + 4);
      float vv[8] = {v0.x, v0.y, v0.z, v0.w, v1.x, v1.y, v1.z, v1.w};
      #pragma unroll
      for (int j = 0; j < 8; ++j) {
        int tok = h * 8 + j;
        sx[tok * 256 + (c ^ ((tok & 15) << 1))] = vv[j];
      }
    }
  }
  __syncthreads();
  const int tok = tid >> 2, g = tid & 3;
  const int swz = (tok & 15) << 1;
  float sum = 0.f;
  for (int q = 0; q < 64; ++q) sum += sx[tok * 256 + ((g * 64 + q) ^ swz)];
  sum += __shfl_xor(sum, 1);
  sum += __shfl_xor(sum, 2);
  const float mu = sum * (1.0f / 256.0f);
  float s2 = 0.f;
  for (int q = 0; q < 64; ++q) {
    float d = sx[tok * 256 + ((g * 64 + q) ^ swz)] - mu;
    s2 += d * d;
  }
  s2 += __shfl_xor(s2, 1);
  s2 += __shfl_xor(s2, 2);
  const float rs = rsqrtf(s2 * (1.0f / 256.0f) + 1e-5f);
  long obase = ((long)blockIdx.x * 64 + tok) * 256 + g * 64;
  for (int q8 = 0; q8 < 8; ++q8) {
    u16 tmp[8];
    #pragma unroll
    for (int e = 0; e < 8; ++e) {
      int c = g * 64 + q8 * 8 + e;
      float v = (sx[tok * 256 + (c ^ swz)] - mu) * rs * nw[c] + nb[c];
      tmp[e] = f2b(v);
    }
    *(ulonglong2*)(xn + obase + q8 * 8) = *(const ulonglong2*)tmp;
  }
}

// ============ 256x256 8-phase GEMM (R3 structure): Y = epi(A @ Bt^T) =======
// Non-persistent, counted vmcnt(4), bijective XCD swizzle, tn fastest.
// Epilogue reuses the staging LDS S (dead after final drain).  128 KiB LDS.
// EPI 1: gelu(acc+bias)  2: Res+gelu(acc+bias)
// EPI 3: Res+gelu(acc+bias) -> out_f [winRow][c=n][tok]  ([n][m] LDS staging)
// EPI 4: acc -> qkv layout [win][head][q|k|v][tok][d]
template <int EPI, int NT, int KD>
__global__ __launch_bounds__(512, 2) void k_gemm256(
    const u16* __restrict__ A, const u16* __restrict__ Bt,
    const float* __restrict__ bias, const u16* __restrict__ Res,
    u16* __restrict__ Y, int N) {
  __shared__ __attribute__((aligned(16))) u16 S[65536];  // 128 KiB
  const int tid = threadIdx.x;
  const int l = tid & 63, wid = tid >> 6;
  const int wm = wid >> 2, wn = wid & 3;

  // m204 bijective XCD swizzle
  const int nwg = gridDim.x;
  const int d = blockIdx.x;
  const int xcd = d & 7, j = d >> 3;
  const int q = nwg >> 3, r8 = nwg & 7;
  const int wrk = (xcd < r8 ? xcd * (q + 1) : r8 * (q + 1) + (xcd - r8) * q) + j;
  const int tm = wrk / NT, tn = wrk % NT;

  const int srow = wid * 8 + (l >> 3);
  const int k0b = ((l & 7) << 4) ^ ((l >> 3) << 4);
  const u16* gA = A + (long)(tm * 256 + srow) * KD + (k0b >> 1);
  const u16* gB = Bt + (long)(tn * 256 + srow) * KD + (k0b >> 1);
  char* ldsS = (char*)S + wid * 1024 + l * 16;
  const char* Sb = (const char*)S;

  f32x4 acc[8][4] = {};
  bf16x8 bfrag[4][2];
  bf16x8 af[2][2];

#define STG(T, ISB, H) do { \
    const u16* g_ = (ISB) ? gB : gA; \
    char* lp_ = ldsS + ((T) & 1) * 65536 + (ISB) * 32768 + (H) * 16384; \
    gload16(g_ + (long)((H) * 128) * KD + (long)(T) * 64, (u16*)lp_); \
    gload16(g_ + (long)((H) * 128 + 64) * KD + (long)(T) * 64, (u16*)(lp_ + 8192)); \
  } while (0)

#define DS_B(T) do { \
    _Pragma("unroll") for (int ni_ = 0; ni_ < 4; ++ni_) { \
      const int r_ = wn * 64 + ni_ * 16 + (l & 15); \
      _Pragma("unroll") for (int kk_ = 0; kk_ < 2; ++kk_) { \
        const int kb_ = kk_ * 64 + ((l >> 4) << 4); \
        bfrag[ni_][kk_] = *(const bf16x8*)(Sb + ((T) & 1) * 65536 + 32768 + r_ * 128 + (kb_ ^ ((r_ & 7) << 4))); \
      } } \
  } while (0)

#define DS_A(T, Q) do { \
    _Pragma("unroll") for (int m2_ = 0; m2_ < 2; ++m2_) { \
      const int r_ = wm * 128 + (2 * (Q) + m2_) * 16 + (l & 15); \
      _Pragma("unroll") for (int kk_ = 0; kk_ < 2; ++kk_) { \
        const int kb_ = kk_ * 64 + ((l >> 4) << 4); \
        af[m2_][kk_] = *(const bf16x8*)(Sb + ((T) & 1) * 65536 + r_ * 128 + (kb_ ^ ((r_ & 7) << 4))); \
      } } \
  } while (0)

#define MFMA16(Q) do { \
    _Pragma("unroll") for (int m2_ = 0; m2_ < 2; ++m2_) \
      _Pragma("unroll") for (int ni_ = 0; ni_ < 4; ++ni_) \
        _Pragma("unroll") for (int kk_ = 0; kk_ < 2; ++kk_) \
          acc[2 * (Q) + m2_][ni_] = __builtin_amdgcn_mfma_f32_16x16x32_bf16( \
              af[m2_][kk_], bfrag[ni_][kk_], acc[2 * (Q) + m2_][ni_], 0, 0, 0); \
  } while (0)

#define BAR_MFMA(Q) do { \
    __builtin_amdgcn_s_barrier(); \
    asm volatile("s_waitcnt lgkmcnt(0)" ::: "memory"); \
    __builtin_amdgcn_sched_barrier(0); \
    __builtin_amdgcn_s_setprio(1); \
    MFMA16(Q); \
    __builtin_amdgcn_s_setprio(0); \
  } while (0)

#define PH_END() do { \
    __builtin_amdgcn_s_barrier(); \
    __builtin_amdgcn_sched_barrier(0); \
  } while (0)

  STG(0, 0, 0); STG(0, 0, 1); STG(0, 1, 0); STG(0, 1, 1);
  STG(1, 0, 0); STG(1, 0, 1); STG(1, 1, 0); STG(1, 1, 1);
  asm volatile("s_waitcnt vmcnt(8)" ::: "memory");
  __builtin_amdgcn_s_barrier();
  __builtin_amdgcn_sched_barrier(0);

  constexpr int nIter = KD >> 7;
  for (int i = 0; i < nIter; ++i) {
    const int t0 = 2 * i, t1 = 2 * i + 1;
    const bool more = (i + 1 < nIter);
    DS_B(t0); DS_A(t0, 0);
    if (i > 0) STG(t1, 0, 0);
    BAR_MFMA(0); PH_END();
    DS_A(t0, 1);
    if (i > 0) STG(t1, 0, 1);
    if (more) STG(t0 + 2, 1, 0);
    BAR_MFMA(1); PH_END();
    DS_A(t0, 2);
    if (more) STG(t0 + 2, 1, 1);
    BAR_MFMA(2); PH_END();
    DS_A(t0, 3);
    BAR_MFMA(3);
    if (more) { asm volatile("s_waitcnt vmcnt(4)" ::: "memory"); }
    else      { asm volatile("s_waitcnt vmcnt(0)" ::: "memory"); }
    PH_END();
    DS_B(t1); DS_A(t1, 0);
    if (more) STG(t0 + 2, 0, 0);
    BAR_MFMA(0); PH_END();
    DS_A(t1, 1);
    if (more) STG(t0 + 2, 0, 1);
    BAR_MFMA(1); PH_END();
    DS_A(t1, 2);
    if (more) STG(t1 + 2, 1, 0);
    BAR_MFMA(2); PH_END();
    DS_A(t1, 3);
    if (more) STG(t1 + 2, 1, 1);
    BAR_MFMA(3);
    if (more) { asm volatile("s_waitcnt vmcnt(4)" ::: "memory"); }
    PH_END();
  }

  // ---- epilogue (staging ring fully drained -> S is free) ----
  if (EPI == 3) {
    float bv[4];
    #pragma unroll
    for (int ni = 0; ni < 4; ++ni)
      bv[ni] = bias[tn * 256 + wn * 64 + ni * 16 + (l & 15)];
    // write phase: [n][m] layout, m-chunk XOR-swizzled for 16B reads
    #pragma unroll
    for (int mi = 0; mi < 8; ++mi) {
      #pragma unroll
      for (int r = 0; r < 4; ++r) {
        const int ml = wm * 128 + mi * 16 + ((l >> 4) << 2) + r;
        #pragma unroll
        for (int ni = 0; ni < 4; ++ni) {
          const int nl = wn * 64 + ni * 16 + (l & 15);
          float v = gelu_f(acc[mi][ni][r] + bv[ni]);
          S[nl * 256 + ((((ml >> 3) ^ ((nl & 7) << 2)) << 3) | (ml & 7))] = f2b(v);
        }
      }
    }
    asm volatile("s_waitcnt lgkmcnt(0)" ::: "memory");
    __builtin_amdgcn_s_barrier();
    // read phase: 16 chunks/thread; chunk = 8 consecutive m at one n
    #pragma unroll
    for (int rd = 0; rd < 16; ++rd) {
      const int id = rd * 512 + tid;
      const int nl = id >> 5, c8 = id & 31;
      ulonglong2 val = *(const ulonglong2*)(S + nl * 256 + ((c8 ^ ((nl & 7) << 2)) << 3));
      u16 tv[8];
      *(ulonglong2*)tv = val;
      const long mg = (long)tm * 256 + c8 * 8;
      const int ng = tn * 256 + nl;
      #pragma unroll
      for (int e = 0; e < 8; ++e) tv[e] = f2b(b2f(tv[e]) + b2f(Res[(mg + e) * N + ng]));
      const long row = (mg >> 6);
      *(ulonglong2*)(Y + (row * 256 + ng) * 64 + (c8 & 7) * 8) = *(const ulonglong2*)tv;
    }
  } else {
    float bv[4];
    if (EPI == 1 || EPI == 2) {
      #pragma unroll
      for (int ni = 0; ni < 4; ++ni)
        bv[ni] = bias[tn * 256 + wn * 64 + ni * 16 + (l & 15)];
    }
    #pragma unroll
    for (int sw = 0; sw < 4; ++sw) {
      #pragma unroll
      for (int mi2 = 0; mi2 < 2; ++mi2) {
        const int mi = 2 * sw + mi2;
        const int lr0 = wm * 32 + mi2 * 16 + ((l >> 4) << 2);
        #pragma unroll
        for (int r = 0; r < 4; ++r) {
          const int lrr = lr0 + r;
          #pragma unroll
          for (int ni = 0; ni < 4; ++ni) {
            float v = acc[mi][ni][r];
            if (EPI == 1 || EPI == 2) v = gelu_f(v + bv[ni]);
            const int col = wn * 64 + ni * 16 + (l & 15);
            S[lrr * 256 + ((((col >> 3) ^ (lrr & 7)) << 3) | (col & 7))] = f2b(v);
          }
        }
      }
      asm volatile("s_waitcnt lgkmcnt(0)" ::: "memory");
      __builtin_amdgcn_s_barrier();
      const int lr2 = tid >> 3;
      const long m = (long)tm * 256 + (lr2 >> 5) * 128 + sw * 32 + (lr2 & 31);
      #pragma unroll
      for (int rd = 0; rd < 4; ++rd) {
        const int chunk = rd * 8 + (tid & 7);
        ulonglong2 val = *(const ulonglong2*)(S + lr2 * 256 + ((chunk ^ (lr2 & 7)) << 3));
        const int n = tn * 256 + chunk * 8;
        if (EPI == 2) {
          u16 tv[8], rv[8];
          *(ulonglong2*)tv = val;
          *(ulonglong2*)rv = *(const ulonglong2*)(Res + m * N + n);
          #pragma unroll
          for (int e = 0; e < 8; ++e) tv[e] = f2b(b2f(tv[e]) + b2f(rv[e]));
          val = *(const ulonglong2*)tv;
        }
        if (EPI == 4) {
          const long win = m >> 6;
          const int t_ = n >> 9, h_ = (n >> 6) & 7, d0 = n & 63;
          *(ulonglong2*)(Y + ((((win * 8 + h_) * 3 + t_) * 64 + (m & 63)) * 64 + d0)) = val;
        } else {
          *(ulonglong2*)(Y + m * N + n) = val;
        }
      }
      if (sw < 3) {
        __builtin_amdgcn_s_barrier();
      }
    }
  }
#undef STG
#undef DS_B
#undef DS_A
#undef MFMA16
#undef BAR_MFMA
#undef PH_END
}

// ---------------- window attention: one block per (window, head) -----------
// qkv layout: [win][head][q|k|v][tok][64] -> block reads one linear 24 KB run.
// Output O staged through sq (dead after QK^T), then coalesced 16B RMW on xf.
// (R8-measured variant: 32 KB LDS, no extra barrier.)
__global__ __launch_bounds__(256) void k_attn(
    const u16* __restrict__ qkv, u16* __restrict__ xf) {
  __shared__ __attribute__((aligned(16))) u16 sq[64 * 64];
  __shared__ __attribute__((aligned(16))) u16 sk[64 * 64];
  __shared__ __attribute__((aligned(16))) u16 sv[64 * 64];  // transposed [d][t]
  __shared__ __attribute__((aligned(16))) u16 sp[64 * 64];
  const int tid = threadIdx.x;
  const int l = tid & 63, w = tid >> 6;
  const int wloc = blockIdx.x >> 3, h = blockIdx.x & 7;
  const long tokbase = (long)wloc * 64;
  const u16* base = qkv + (long)blockIdx.x * 12288;

  #pragma unroll
  for (int rd = 0; rd < 6; ++rd) {
    const int cid = rd * 256 + tid;
    ulonglong2 v16 = *(const ulonglong2*)(base + (long)cid * 8);
    const int t = (cid >> 3) & 63, d0 = (cid & 7) << 3;
    if (rd < 2) {
      *(ulonglong2*)((char*)sq + t * 128 + ((d0 * 2) ^ ((t & 7) << 4))) = v16;
    } else if (rd < 4) {
      *(ulonglong2*)((char*)sk + t * 128 + ((d0 * 2) ^ ((t & 7) << 4))) = v16;
    } else {
      u16 vv[8];
      *(ulonglong2*)vv = v16;
      #pragma unroll
      for (int e = 0; e < 8; ++e) {
        int r = d0 + e;
        *(u16*)((char*)sv + r * 128 + ((t * 2) ^ ((r & 7) << 4))) = vv[e];
      }
    }
  }
  __syncthreads();

  f32x4 accs[4] = {};
  #pragma unroll
  for (int ks = 0; ks < 2; ++ks) {
    int kb = ks * 64 + ((l >> 4) << 4);
    int ra = w * 16 + (l & 15);
    bf16x8 aq = *(const bf16x8*)((char*)sq + ra * 128 + (kb ^ ((ra & 7) << 4)));
    #pragma unroll
    for (int cf = 0; cf < 4; ++cf) {
      int rb = cf * 16 + (l & 15);
      bf16x8 bk = *(const bf16x8*)((char*)sk + rb * 128 + (kb ^ ((rb & 7) << 4)));
      accs[cf] = __builtin_amdgcn_mfma_f32_16x16x32_bf16(aq, bk, accs[cf], 0, 0, 0);
    }
  }
  const float scale = 0.17677669529663687f;
  float pv[4][4];
  #pragma unroll
  for (int r = 0; r < 4; ++r) {
    float m = -1e30f;
    #pragma unroll
    for (int cf = 0; cf < 4; ++cf) {
      pv[cf][r] = accs[cf][r] * scale;
      m = fmaxf(m, pv[cf][r]);
    }
    for (int off = 1; off < 16; off <<= 1) m = fmaxf(m, __shfl_xor(m, off));
    float s = 0.f;
    #pragma unroll
    for (int cf = 0; cf < 4; ++cf) { pv[cf][r] = __expf(pv[cf][r] - m); s += pv[cf][r]; }
    for (int off = 1; off < 16; off <<= 1) s += __shfl_xor(s, off);
    float inv = 1.0f / s;
    #pragma unroll
    for (int cf = 0; cf < 4; ++cf) pv[cf][r] *= inv;
  }
  #pragma unroll
  for (int cf = 0; cf < 4; ++cf)
    #pragma unroll
    for (int r = 0; r < 4; ++r) {
      int pr = w * 16 + ((l >> 4) << 2) + r, pc = cf * 16 + (l & 15);
      *(u16*)((char*)sp + pr * 128 + ((pc * 2) ^ ((pr & 7) << 4))) = f2b(pv[cf][r]);
    }
  __syncthreads();

  f32x4 acco[4] = {};
  #pragma unroll
  for (int ks = 0; ks < 2; ++ks) {
    int kb = ks * 64 + ((l >> 4) << 4);
    int ra = w * 16 + (l & 15);
    bf16x8 ap = *(const bf16x8*)((char*)sp + ra * 128 + (kb ^ ((ra & 7) << 4)));
    #pragma unroll
    for (int cf = 0; cf < 4; ++cf) {
      int rb = cf * 16 + (l & 15);
      bf16x8 bvv = *(const bf16x8*)((char*)sv + rb * 128 + (kb ^ ((rb & 7) << 4)));
      acco[cf] = __builtin_amdgcn_mfma_f32_16x16x32_bf16(ap, bvv, acco[cf], 0, 0, 0);
    }
  }
  // stage O -> sq (dead after QK^T)
  #pragma unroll
  for (int cf = 0; cf < 4; ++cf)
    #pragma unroll
    for (int r = 0; r < 4; ++r) {
      int orow = w * 16 + ((l >> 4) << 2) + r, ocol = cf * 16 + (l & 15);
      *(u16*)((char*)sq + orow * 128 + ((ocol * 2) ^ ((orow & 7) << 4))) = f2b(acco[cf][r]);
    }
  __syncthreads();
  // coalesced RMW on xf: 4 threads/row x 32B
  {
    const int row = tid >> 2, c32 = tid & 3;
    const long gaddr = (tokbase + row) * 512 + h * 64 + c32 * 16;
    #pragma unroll
    for (int hh = 0; hh < 2; ++hh) {
      const int colb = c32 * 32 + hh * 16;
      ulonglong2 ov = *(const ulonglong2*)((char*)sq + row * 128 + (colb ^ ((row & 7) << 4)));
      ulonglong2 xv = *(const ulonglong2*)(xf + gaddr + hh * 8);
      u16 o16[8], x16[8];
      *(ulonglong2*)o16 = ov;
      *(ulonglong2*)x16 = xv;
      #pragma unroll
      for (int e = 0; e < 8; ++e) x16[e] = f2b(b2f(x16[e]) + b2f(o16[e]));
      *(ulonglong2*)(xf + gaddr + hh * 8) = *(const ulonglong2*)x16;
    }
  }
}

// ---------------- final assemble: lanes along W, out_f in [row][c][tok] ----
__global__ __launch_bounds__(256) void k_assemble(
    const float* __restrict__ fm, const u16* __restrict__ out_f,
    const int* __restrict__ win2row, float* __restrict__ out) {
  const int tid = threadIdx.x;
  const int bq = blockIdx.x;            // (b*256 + c)*64 + hw
  const int hw = bq & 63, c = (bq >> 6) & 255, b = bq >> 14;
  const int w0 = (tid & 127) << 2;      // 0..508 step 4
  const int hlo = tid >> 7;             // 0/1
  const int win = hw * 64 + (w0 >> 3);
  const int r = win2row[b * 4096 + win];
  const u16* ofb = out_f + ((long)(r < 0 ? 0 : r) * 256 + c) * 64 + (w0 & 7);
  const long base = ((long)(b * 256 + c) * 512 + hw * 8) * 512 + w0;
  #pragma unroll
  for (int jj = 0; jj < 4; ++jj) {
    const int h = jj * 2 + hlo;
    float4 v = *(const float4*)(fm + base + (long)h * 512);
    if (r >= 0) {
      ushort4 ov = *(const ushort4*)(ofb + h * 8);
      v.x += b2f(ov.x);
      v.y += b2f(ov.y);
      v.z += b2f(ov.z);
      v.w += b2f(ov.w);
    }
    *(float4*)(out + base + (long)h * 512) = v;
  }
}

// ============================ host launcher =================================
extern "C" void kernel_launch(void* const* d_in, const int* in_sizes, int n_in,
                              void* d_out, int out_size, void* d_ws, size_t ws_size,
                              hipStream_t stream) {
  const float* fm     = (const float*)d_in[0];
  const float* unc    = (const float*)d_in[1];
  const float* nw     = (const float*)d_in[2];
  const float* nb     = (const float*)d_in[3];
  const float* w_lin0 = (const float*)d_in[4];
  const float* b_lin0 = (const float*)d_in[5];
  const float* w_qkv0 = (const float*)d_in[6];
  const float* w_lin1 = (const float*)d_in[7];
  const float* b_lin1 = (const float*)d_in[8];
  const float* w_qkv1 = (const float*)d_in[9];
  const float* w_proj = (const float*)d_in[10];
  const float* b_proj = (const float*)d_in[11];
  float* out = (float*)d_out;

  const int nWF = 1228, totWin = 2456;
  const long totTok = (long)totWin * 64;

  char* p = (char*)d_ws;
  auto alloc = [&](size_t bytes) {
    char* r = p;
    p += (bytes + 255) & ~(size_t)255;
    return r;
  };
  float* scores = (float*)alloc(8192 * 4);
  int* win2row  = (int*)alloc(8192 * 4);
  int* row2win  = (int*)alloc(totWin * 4);
  u16* wT       = (u16*)alloc((size_t)2097152 * 2);
  u16* out_f    = (u16*)alloc((size_t)(totTok + 256) * 256 * 2);
  size_t persist = (size_t)(p - (char*)d_ws);

  // Chunk the layer pipeline so qkvb (and all inter-kernel intermediates) fit
  // in the 256 MB Infinity Cache: 4 chunks -> qkvb ~121 MB, xn/xfa/xfb ~10-40.
  // The qkv-write -> attn-read round trip then stays in L3 instead of HBM.
  int wpc = totWin;
  {
    const int cands[5] = {4, 8, 16, 32, 64};
    for (int ci = 0; ci < 5; ++ci) {
      int n = cands[ci];
      int wp = ((totWin + n - 1) / n + 3) & ~3;
      size_t mc = (size_t)wp * 64;
      size_t need = persist + 4096 +
                    ((mc * 256 * 2 + 255) & ~(size_t)255) +
                    2 * ((mc * 512 * 2 + 255) & ~(size_t)255) +
                    ((mc * 1536 * 2 + 255) & ~(size_t)255);
      if (need <= ws_size) { wpc = wp; break; }
    }
  }
  long mcap = (long)wpc * 64;
  u16* xn   = (u16*)alloc((size_t)mcap * 256 * 2);
  u16* xfa  = (u16*)alloc((size_t)mcap * 512 * 2);
  u16* xfb  = (u16*)alloc((size_t)mcap * 512 * 2);
  u16* qkvb = (u16*)alloc((size_t)mcap * 1536 * 2);

  u16* wT_lin0 = wT;
  u16* wT_qkv0 = wT + 131072;
  u16* wT_lin1 = wT + 917504;
  u16* wT_qkv1 = wT + 1179648;
  u16* wT_proj = wT + 1966080;
  k_transpose_w<<<(131072 + 255) / 256, 256, 0, stream>>>(w_lin0, wT_lin0, 256, 512);
  k_transpose_w<<<(786432 + 255) / 256, 256, 0, stream>>>(w_qkv0, wT_qkv0, 512, 1536);
  k_transpose_w<<<(262144 + 255) / 256, 256, 0, stream>>>(w_lin1, wT_lin1, 512, 512);
  k_transpose_w<<<(786432 + 255) / 256, 256, 0, stream>>>(w_qkv1, wT_qkv1, 512, 1536);
  k_transpose_w<<<(131072 + 255) / 256, 256, 0, stream>>>(w_proj, wT_proj, 512, 256);

  k_scores<<<32, 256, 0, stream>>>(unc, scores);
  k_topk<<<2, 1024, 0, stream>>>(scores, row2win, win2row, nWF);

  for (int w0 = 0; w0 < totWin; w0 += wpc) {
    int rem = totWin - w0;
    int wn = (wpc < rem) ? wpc : rem;       // multiple of 4
    int mT = wn / 4;                         // (wn*64)/256
    k_gather_ln<<<wn, 256, 0, stream>>>(fm, nw, nb, row2win, xn, w0);
    k_gemm256<1, 2, 256><<<mT * 2, 512, 0, stream>>>(xn, wT_lin0, b_lin0, nullptr, xfa, 512);
    k_gemm256<4, 6, 512><<<mT * 6, 512, 0, stream>>>(xfa, wT_qkv0, nullptr, nullptr, qkvb, 1536);
    k_attn<<<wn * 8, 256, 0, stream>>>(qkvb, xfa);
    k_gemm256<2, 2, 512><<<mT * 2, 512, 0, stream>>>(xfa, wT_lin1, b_lin1, xfa, xfb, 512);
    k_gemm256<4, 6, 512><<<mT * 6, 512, 0, stream>>>(xfb, wT_qkv1, nullptr, nullptr, qkvb, 1536);
    k_attn<<<wn * 8, 256, 0, stream>>>(qkvb, xfb);
    k_gemm256<3, 1, 512><<<mT * 1, 512, 0, stream>>>(xfb, wT_proj, b_proj, xn,
                                                     out_f + (long)w0 * 16384, 256);
  }
  k_assemble<<<32768, 256, 0, stream>>>(fm, out_f, win2row, out);
}

// Round 13
// 1758.413 us; speedup vs baseline: 1.1593x; 1.1593x over previous
//
#include <hip/hip_runtime.h>
#include <math.h>

typedef unsigned short u16;
typedef unsigned int   u32;
typedef __attribute__((ext_vector_type(8))) short bf16x8;
typedef __attribute__((ext_vector_type(4))) float f32x4;

#define DEV static __device__ __forceinline__

DEV u16 f2b(float f) {
  union { float f; u32 u; } v; v.f = f;
  u32 r = v.u + 0x7FFFu + ((v.u >> 16) & 1u);
  return (u16)(r >> 16);
}
DEV float b2f(u16 h) {
  union { u32 u; float f; } v; v.u = ((u32)h) << 16;
  return v.f;
}
DEV float gelu_f(float x) { return 0.5f * x * (1.0f + erff(x * 0.70710678118654752f)); }

DEV void gload16(const u16* g, u16* l) {
  __builtin_amdgcn_global_load_lds(
      (const __attribute__((address_space(1))) void*)g,
      (__attribute__((address_space(3))) void*)l, 16, 0, 0);
}

// ---------------- weight transpose: fp32 (K,N) -> bf16 (N,K) ----------------
__global__ void k_transpose_w(const float* __restrict__ src, u16* __restrict__ dst,
                              int K, int N) {
  long t = (long)blockIdx.x * 256 + threadIdx.x;
  if (t >= (long)K * N) return;
  int n = (int)(t / K), k = (int)(t % K);
  dst[t] = f2b(src[(long)k * N + n]);
}

// ---------------- per-window uncertainty mean (numpy pairwise order) --------
__global__ void k_scores(const float* __restrict__ unc, float* __restrict__ scores) {
  int id = blockIdx.x * 256 + threadIdx.x;
  if (id >= 8192) return;
  int b = id >> 12, win = id & 4095;
  int h0 = (win >> 6) << 3, w0 = (win & 63) << 3;
  float r[8] = {0.f,0.f,0.f,0.f,0.f,0.f,0.f,0.f};
  for (int i = 0; i < 8; ++i) {
    long base = ((long)(b * 512 + h0 + i)) * 512 + w0;
    #pragma unroll
    for (int j = 0; j < 8; ++j) r[j] += unc[base + j];
  }
  float s = ((r[0] + r[1]) + (r[2] + r[3])) + ((r[4] + r[5]) + (r[6] + r[7]));
  scores[id] = s * (1.0f / 64.0f);
}

// ---------------- top-k (1228 of 4096) per batch: bitonic, tie -> lower idx --
__global__ __launch_bounds__(1024) void k_topk(
    const float* __restrict__ scores, int* __restrict__ row2win,
    int* __restrict__ win2row, int nWF) {
  __shared__ float ls[4096];
  __shared__ int   li[4096];
  const int b = blockIdx.x;
  const int tid = threadIdx.x;
  for (int i = tid; i < 4096; i += 1024) {
    ls[i] = scores[b * 4096 + i];
    li[i] = i;
    win2row[b * 4096 + i] = -1;
  }
  __syncthreads();
  for (int k = 2; k <= 4096; k <<= 1) {
    for (int j = k >> 1; j > 0; j >>= 1) {
      for (int t = tid; t < 2048; t += 1024) {
        int i = ((t / j) * (j << 1)) + (t % j);
        int ixj = i + j;
        bool up = ((i & k) == 0);
        float sa = ls[i], sb = ls[ixj];
        int ia = li[i], ib = li[ixj];
        bool g = (sa > sb) || (sa == sb && ia < ib);
        if (g != up) { ls[i] = sb; ls[ixj] = sa; li[i] = ib; li[ixj] = ia; }
      }
      __syncthreads();
    }
  }
  for (int r = tid; r < nWF; r += 1024) {
    int win = li[r];
    row2win[b * nWF + r] = (b << 12) | win;
    win2row[b * 4096 + win] = b * nWF + r;
  }
}

// ---------------- gather selected window + LayerNorm -> xn (bf16) ----------
__global__ __launch_bounds__(256) void k_gather_ln(
    const float* __restrict__ fm, const float* __restrict__ nw,
    const float* __restrict__ nb, const int* __restrict__ row2win,
    u16* __restrict__ xn, int winStart) {
  __shared__ float sx[64 * 256];
  const int tid = threadIdx.x;
  const int rw = row2win[winStart + blockIdx.x];
  const int b = rw >> 12, win = rw & 4095;
  const int h0 = (win >> 6) << 3, w0 = (win & 63) << 3;
  {
    const int c8 = tid >> 3, h = tid & 7;
    #pragma unroll
    for (int cc = 0; cc < 8; ++cc) {
      const int c = cc * 32 + c8;
      long base = ((long)(b * 256 + c) * 512 + h0 + h) * 512 + w0;
      float4 v0 = *(const float4*)(fm + base);
      float4 v1 = *(const float4*)(fm + base + 4);
      float vv[8] = {v0.x, v0.y, v0.z, v0.w, v1.x, v1.y, v1.z, v1.w};
      #pragma unroll
      for (int j = 0; j < 8; ++j) {
        int tok = h * 8 + j;
        sx[tok * 256 + (c ^ ((tok & 15) << 1))] = vv[j];
      }
    }
  }
  __syncthreads();
  const int tok = tid >> 2, g = tid & 3;
  const int swz = (tok & 15) << 1;
  float sum = 0.f;
  for (int q = 0; q < 64; ++q) sum += sx[tok * 256 + ((g * 64 + q) ^ swz)];
  sum += __shfl_xor(sum, 1);
  sum += __shfl_xor(sum, 2);
  const float mu = sum * (1.0f / 256.0f);
  float s2 = 0.f;
  for (int q = 0; q < 64; ++q) {
    float d = sx[tok * 256 + ((g * 64 + q) ^ swz)] - mu;
    s2 += d * d;
  }
  s2 += __shfl_xor(s2, 1);
  s2 += __shfl_xor(s2, 2);
  const float rs = rsqrtf(s2 * (1.0f / 256.0f) + 1e-5f);
  long obase = ((long)blockIdx.x * 64 + tok) * 256 + g * 64;
  for (int q8 = 0; q8 < 8; ++q8) {
    u16 tmp[8];
    #pragma unroll
    for (int e = 0; e < 8; ++e) {
      int c = g * 64 + q8 * 8 + e;
      float v = (sx[tok * 256 + (c ^ swz)] - mu) * rs * nw[c] + nb[c];
      tmp[e] = f2b(v);
    }
    *(ulonglong2*)(xn + obase + q8 * 8) = *(const ulonglong2*)tmp;
  }
}

// ============ 256x256 8-phase GEMM (R3 structure): Y = epi(A @ Bt^T) =======
// Non-persistent, counted vmcnt(4), bijective XCD swizzle, tn fastest.
// Epilogue reuses the staging LDS S (dead after final drain).  128 KiB LDS.
// EPI 1: gelu(acc+bias)  2: Res+gelu(acc+bias)
// EPI 3: Res+gelu(acc+bias) -> out_f [winRow][c=n][tok]  ([n][m] LDS staging)
// EPI 4: acc -> qkv layout [win][head][q|k|v][tok][d]
template <int EPI, int NT, int KD>
__global__ __launch_bounds__(512, 2) void k_gemm256(
    const u16* __restrict__ A, const u16* __restrict__ Bt,
    const float* __restrict__ bias, const u16* __restrict__ Res,
    u16* __restrict__ Y, int N) {
  __shared__ __attribute__((aligned(16))) u16 S[65536];  // 128 KiB
  const int tid = threadIdx.x;
  const int l = tid & 63, wid = tid >> 6;
  const int wm = wid >> 2, wn = wid & 3;

  // m204 bijective XCD swizzle
  const int nwg = gridDim.x;
  const int d = blockIdx.x;
  const int xcd = d & 7, j = d >> 3;
  const int q = nwg >> 3, r8 = nwg & 7;
  const int wrk = (xcd < r8 ? xcd * (q + 1) : r8 * (q + 1) + (xcd - r8) * q) + j;
  const int tm = wrk / NT, tn = wrk % NT;

  const int srow = wid * 8 + (l >> 3);
  const int k0b = ((l & 7) << 4) ^ ((l >> 3) << 4);
  const u16* gA = A + (long)(tm * 256 + srow) * KD + (k0b >> 1);
  const u16* gB = Bt + (long)(tn * 256 + srow) * KD + (k0b >> 1);
  char* ldsS = (char*)S + wid * 1024 + l * 16;
  const char* Sb = (const char*)S;

  f32x4 acc[8][4] = {};
  bf16x8 bfrag[4][2];
  bf16x8 af[2][2];

#define STG(T, ISB, H) do { \
    const u16* g_ = (ISB) ? gB : gA; \
    char* lp_ = ldsS + ((T) & 1) * 65536 + (ISB) * 32768 + (H) * 16384; \
    gload16(g_ + (long)((H) * 128) * KD + (long)(T) * 64, (u16*)lp_); \
    gload16(g_ + (long)((H) * 128 + 64) * KD + (long)(T) * 64, (u16*)(lp_ + 8192)); \
  } while (0)

#define DS_B(T) do { \
    _Pragma("unroll") for (int ni_ = 0; ni_ < 4; ++ni_) { \
      const int r_ = wn * 64 + ni_ * 16 + (l & 15); \
      _Pragma("unroll") for (int kk_ = 0; kk_ < 2; ++kk_) { \
        const int kb_ = kk_ * 64 + ((l >> 4) << 4); \
        bfrag[ni_][kk_] = *(const bf16x8*)(Sb + ((T) & 1) * 65536 + 32768 + r_ * 128 + (kb_ ^ ((r_ & 7) << 4))); \
      } } \
  } while (0)

#define DS_A(T, Q) do { \
    _Pragma("unroll") for (int m2_ = 0; m2_ < 2; ++m2_) { \
      const int r_ = wm * 128 + (2 * (Q) + m2_) * 16 + (l & 15); \
      _Pragma("unroll") for (int kk_ = 0; kk_ < 2; ++kk_) { \
        const int kb_ = kk_ * 64 + ((l >> 4) << 4); \
        af[m2_][kk_] = *(const bf16x8*)(Sb + ((T) & 1) * 65536 + r_ * 128 + (kb_ ^ ((r_ & 7) << 4))); \
      } } \
  } while (0)

#define MFMA16(Q) do { \
    _Pragma("unroll") for (int m2_ = 0; m2_ < 2; ++m2_) \
      _Pragma("unroll") for (int ni_ = 0; ni_ < 4; ++ni_) \
        _Pragma("unroll") for (int kk_ = 0; kk_ < 2; ++kk_) \
          acc[2 * (Q) + m2_][ni_] = __builtin_amdgcn_mfma_f32_16x16x32_bf16( \
              af[m2_][kk_], bfrag[ni_][kk_], acc[2 * (Q) + m2_][ni_], 0, 0, 0); \
  } while (0)

#define BAR_MFMA(Q) do { \
    __builtin_amdgcn_s_barrier(); \
    asm volatile("s_waitcnt lgkmcnt(0)" ::: "memory"); \
    __builtin_amdgcn_sched_barrier(0); \
    __builtin_amdgcn_s_setprio(1); \
    MFMA16(Q); \
    __builtin_amdgcn_s_setprio(0); \
  } while (0)

#define PH_END() do { \
    __builtin_amdgcn_s_barrier(); \
    __builtin_amdgcn_sched_barrier(0); \
  } while (0)

  STG(0, 0, 0); STG(0, 0, 1); STG(0, 1, 0); STG(0, 1, 1);
  STG(1, 0, 0); STG(1, 0, 1); STG(1, 1, 0); STG(1, 1, 1);
  asm volatile("s_waitcnt vmcnt(8)" ::: "memory");
  __builtin_amdgcn_s_barrier();
  __builtin_amdgcn_sched_barrier(0);

  constexpr int nIter = KD >> 7;
  for (int i = 0; i < nIter; ++i) {
    const int t0 = 2 * i, t1 = 2 * i + 1;
    const bool more = (i + 1 < nIter);
    DS_B(t0); DS_A(t0, 0);
    if (i > 0) STG(t1, 0, 0);
    BAR_MFMA(0); PH_END();
    DS_A(t0, 1);
    if (i > 0) STG(t1, 0, 1);
    if (more) STG(t0 + 2, 1, 0);
    BAR_MFMA(1); PH_END();
    DS_A(t0, 2);
    if (more) STG(t0 + 2, 1, 1);
    BAR_MFMA(2); PH_END();
    DS_A(t0, 3);
    BAR_MFMA(3);
    if (more) { asm volatile("s_waitcnt vmcnt(4)" ::: "memory"); }
    else      { asm volatile("s_waitcnt vmcnt(0)" ::: "memory"); }
    PH_END();
    DS_B(t1); DS_A(t1, 0);
    if (more) STG(t0 + 2, 0, 0);
    BAR_MFMA(0); PH_END();
    DS_A(t1, 1);
    if (more) STG(t0 + 2, 0, 1);
    BAR_MFMA(1); PH_END();
    DS_A(t1, 2);
    if (more) STG(t1 + 2, 1, 0);
    BAR_MFMA(2); PH_END();
    DS_A(t1, 3);
    if (more) STG(t1 + 2, 1, 1);
    BAR_MFMA(3);
    if (more) { asm volatile("s_waitcnt vmcnt(4)" ::: "memory"); }
    PH_END();
  }

  // ---- epilogue (staging ring fully drained -> S is free) ----
  if (EPI == 3) {
    float bv[4];
    #pragma unroll
    for (int ni = 0; ni < 4; ++ni)
      bv[ni] = bias[tn * 256 + wn * 64 + ni * 16 + (l & 15)];
    // write phase: [n][m] layout, m-chunk XOR-swizzled for 16B reads
    #pragma unroll
    for (int mi = 0; mi < 8; ++mi) {
      #pragma unroll
      for (int r = 0; r < 4; ++r) {
        const int ml = wm * 128 + mi * 16 + ((l >> 4) << 2) + r;
        #pragma unroll
        for (int ni = 0; ni < 4; ++ni) {
          const int nl = wn * 64 + ni * 16 + (l & 15);
          float v = gelu_f(acc[mi][ni][r] + bv[ni]);
          S[nl * 256 + ((((ml >> 3) ^ ((nl & 7) << 2)) << 3) | (ml & 7))] = f2b(v);
        }
      }
    }
    asm volatile("s_waitcnt lgkmcnt(0)" ::: "memory");
    __builtin_amdgcn_s_barrier();
    // read phase: 16 chunks/thread; chunk = 8 consecutive m at one n
    #pragma unroll
    for (int rd = 0; rd < 16; ++rd) {
      const int id = rd * 512 + tid;
      const int nl = id >> 5, c8 = id & 31;
      ulonglong2 val = *(const ulonglong2*)(S + nl * 256 + ((c8 ^ ((nl & 7) << 2)) << 3));
      u16 tv[8];
      *(ulonglong2*)tv = val;
      const long mg = (long)tm * 256 + c8 * 8;
      const int ng = tn * 256 + nl;
      #pragma unroll
      for (int e = 0; e < 8; ++e) tv[e] = f2b(b2f(tv[e]) + b2f(Res[(mg + e) * N + ng]));
      const long row = (mg >> 6);
      *(ulonglong2*)(Y + (row * 256 + ng) * 64 + (c8 & 7) * 8) = *(const ulonglong2*)tv;
    }
  } else {
    float bv[4];
    if (EPI == 1 || EPI == 2) {
      #pragma unroll
      for (int ni = 0; ni < 4; ++ni)
        bv[ni] = bias[tn * 256 + wn * 64 + ni * 16 + (l & 15)];
    }
    #pragma unroll
    for (int sw = 0; sw < 4; ++sw) {
      #pragma unroll
      for (int mi2 = 0; mi2 < 2; ++mi2) {
        const int mi = 2 * sw + mi2;
        const int lr0 = wm * 32 + mi2 * 16 + ((l >> 4) << 2);
        #pragma unroll
        for (int r = 0; r < 4; ++r) {
          const int lrr = lr0 + r;
          #pragma unroll
          for (int ni = 0; ni < 4; ++ni) {
            float v = acc[mi][ni][r];
            if (EPI == 1 || EPI == 2) v = gelu_f(v + bv[ni]);
            const int col = wn * 64 + ni * 16 + (l & 15);
            S[lrr * 256 + ((((col >> 3) ^ (lrr & 7)) << 3) | (col & 7))] = f2b(v);
          }
        }
      }
      asm volatile("s_waitcnt lgkmcnt(0)" ::: "memory");
      __builtin_amdgcn_s_barrier();
      const int lr2 = tid >> 3;
      const long m = (long)tm * 256 + (lr2 >> 5) * 128 + sw * 32 + (lr2 & 31);
      #pragma unroll
      for (int rd = 0; rd < 4; ++rd) {
        const int chunk = rd * 8 + (tid & 7);
        ulonglong2 val = *(const ulonglong2*)(S + lr2 * 256 + ((chunk ^ (lr2 & 7)) << 3));
        const int n = tn * 256 + chunk * 8;
        if (EPI == 2) {
          u16 tv[8], rv[8];
          *(ulonglong2*)tv = val;
          *(ulonglong2*)rv = *(const ulonglong2*)(Res + m * N + n);
          #pragma unroll
          for (int e = 0; e < 8; ++e) tv[e] = f2b(b2f(tv[e]) + b2f(rv[e]));
          val = *(const ulonglong2*)tv;
        }
        if (EPI == 4) {
          const long win = m >> 6;
          const int t_ = n >> 9, h_ = (n >> 6) & 7, d0 = n & 63;
          *(ulonglong2*)(Y + ((((win * 8 + h_) * 3 + t_) * 64 + (m & 63)) * 64 + d0)) = val;
        } else {
          *(ulonglong2*)(Y + m * N + n) = val;
        }
      }
      if (sw < 3) {
        __builtin_amdgcn_s_barrier();
      }
    }
  }
#undef STG
#undef DS_B
#undef DS_A
#undef MFMA16
#undef BAR_MFMA
#undef PH_END
}

// ---------------- window attention: one block per (window, head) -----------
// qkv layout: [win][head][q|k|v][tok][64] -> block reads one linear 24 KB run.
// Output O staged through sq (dead after QK^T), then coalesced 16B RMW on xf.
// (R8/R9-measured variant: 32 KB LDS.)
__global__ __launch_bounds__(256) void k_attn(
    const u16* __restrict__ qkv, u16* __restrict__ xf) {
  __shared__ __attribute__((aligned(16))) u16 sq[64 * 64];
  __shared__ __attribute__((aligned(16))) u16 sk[64 * 64];
  __shared__ __attribute__((aligned(16))) u16 sv[64 * 64];  // transposed [d][t]
  __shared__ __attribute__((aligned(16))) u16 sp[64 * 64];
  const int tid = threadIdx.x;
  const int l = tid & 63, w = tid >> 6;
  const int wloc = blockIdx.x >> 3, h = blockIdx.x & 7;
  const long tokbase = (long)wloc * 64;
  const u16* base = qkv + (long)blockIdx.x * 12288;

  #pragma unroll
  for (int rd = 0; rd < 6; ++rd) {
    const int cid = rd * 256 + tid;
    ulonglong2 v16 = *(const ulonglong2*)(base + (long)cid * 8);
    const int t = (cid >> 3) & 63, d0 = (cid & 7) << 3;
    if (rd < 2) {
      *(ulonglong2*)((char*)sq + t * 128 + ((d0 * 2) ^ ((t & 7) << 4))) = v16;
    } else if (rd < 4) {
      *(ulonglong2*)((char*)sk + t * 128 + ((d0 * 2) ^ ((t & 7) << 4))) = v16;
    } else {
      u16 vv[8];
      *(ulonglong2*)vv = v16;
      #pragma unroll
      for (int e = 0; e < 8; ++e) {
        int r = d0 + e;
        *(u16*)((char*)sv + r * 128 + ((t * 2) ^ ((r & 7) << 4))) = vv[e];
      }
    }
  }
  __syncthreads();

  f32x4 accs[4] = {};
  #pragma unroll
  for (int ks = 0; ks < 2; ++ks) {
    int kb = ks * 64 + ((l >> 4) << 4);
    int ra = w * 16 + (l & 15);
    bf16x8 aq = *(const bf16x8*)((char*)sq + ra * 128 + (kb ^ ((ra & 7) << 4)));
    #pragma unroll
    for (int cf = 0; cf < 4; ++cf) {
      int rb = cf * 16 + (l & 15);
      bf16x8 bk = *(const bf16x8*)((char*)sk + rb * 128 + (kb ^ ((rb & 7) << 4)));
      accs[cf] = __builtin_amdgcn_mfma_f32_16x16x32_bf16(aq, bk, accs[cf], 0, 0, 0);
    }
  }
  const float scale = 0.17677669529663687f;
  float pv[4][4];
  #pragma unroll
  for (int r = 0; r < 4; ++r) {
    float m = -1e30f;
    #pragma unroll
    for (int cf = 0; cf < 4; ++cf) {
      pv[cf][r] = accs[cf][r] * scale;
      m = fmaxf(m, pv[cf][r]);
    }
    for (int off = 1; off < 16; off <<= 1) m = fmaxf(m, __shfl_xor(m, off));
    float s = 0.f;
    #pragma unroll
    for (int cf = 0; cf < 4; ++cf) { pv[cf][r] = __expf(pv[cf][r] - m); s += pv[cf][r]; }
    for (int off = 1; off < 16; off <<= 1) s += __shfl_xor(s, off);
    float inv = 1.0f / s;
    #pragma unroll
    for (int cf = 0; cf < 4; ++cf) pv[cf][r] *= inv;
  }
  #pragma unroll
  for (int cf = 0; cf < 4; ++cf)
    #pragma unroll
    for (int r = 0; r < 4; ++r) {
      int pr = w * 16 + ((l >> 4) << 2) + r, pc = cf * 16 + (l & 15);
      *(u16*)((char*)sp + pr * 128 + ((pc * 2) ^ ((pr & 7) << 4))) = f2b(pv[cf][r]);
    }
  __syncthreads();

  f32x4 acco[4] = {};
  #pragma unroll
  for (int ks = 0; ks < 2; ++ks) {
    int kb = ks * 64 + ((l >> 4) << 4);
    int ra = w * 16 + (l & 15);
    bf16x8 ap = *(const bf16x8*)((char*)sp + ra * 128 + (kb ^ ((ra & 7) << 4)));
    #pragma unroll
    for (int cf = 0; cf < 4; ++cf) {
      int rb = cf * 16 + (l & 15);
      bf16x8 bvv = *(const bf16x8*)((char*)sv + rb * 128 + (kb ^ ((rb & 7) << 4)));
      acco[cf] = __builtin_amdgcn_mfma_f32_16x16x32_bf16(ap, bvv, acco[cf], 0, 0, 0);
    }
  }
  // stage O -> sq (dead after QK^T)
  #pragma unroll
  for (int cf = 0; cf < 4; ++cf)
    #pragma unroll
    for (int r = 0; r < 4; ++r) {
      int orow = w * 16 + ((l >> 4) << 2) + r, ocol = cf * 16 + (l & 15);
      *(u16*)((char*)sq + orow * 128 + ((ocol * 2) ^ ((orow & 7) << 4))) = f2b(acco[cf][r]);
    }
  __syncthreads();
  // coalesced RMW on xf: 4 threads/row x 32B
  {
    const int row = tid >> 2, c32 = tid & 3;
    const long gaddr = (tokbase + row) * 512 + h * 64 + c32 * 16;
    #pragma unroll
    for (int hh = 0; hh < 2; ++hh) {
      const int colb = c32 * 32 + hh * 16;
      ulonglong2 ov = *(const ulonglong2*)((char*)sq + row * 128 + (colb ^ ((row & 7) << 4)));
      ulonglong2 xv = *(const ulonglong2*)(xf + gaddr + hh * 8);
      u16 o16[8], x16[8];
      *(ulonglong2*)o16 = ov;
      *(ulonglong2*)x16 = xv;
      #pragma unroll
      for (int e = 0; e < 8; ++e) x16[e] = f2b(b2f(x16[e]) + b2f(o16[e]));
      *(ulonglong2*)(xf + gaddr + hh * 8) = *(const ulonglong2*)x16;
    }
  }
}

// ---------------- final assemble: lanes along W, out_f in [row][c][tok] ----
__global__ __launch_bounds__(256) void k_assemble(
    const float* __restrict__ fm, const u16* __restrict__ out_f,
    const int* __restrict__ win2row, float* __restrict__ out) {
  const int tid = threadIdx.x;
  const int bq = blockIdx.x;            // (b*256 + c)*64 + hw
  const int hw = bq & 63, c = (bq >> 6) & 255, b = bq >> 14;
  const int w0 = (tid & 127) << 2;      // 0..508 step 4
  const int hlo = tid >> 7;             // 0/1
  const int win = hw * 64 + (w0 >> 3);
  const int r = win2row[b * 4096 + win];
  const u16* ofb = out_f + ((long)(r < 0 ? 0 : r) * 256 + c) * 64 + (w0 & 7);
  const long base = ((long)(b * 256 + c) * 512 + hw * 8) * 512 + w0;
  #pragma unroll
  for (int jj = 0; jj < 4; ++jj) {
    const int h = jj * 2 + hlo;
    float4 v = *(const float4*)(fm + base + (long)h * 512);
    if (r >= 0) {
      ushort4 ov = *(const ushort4*)(ofb + h * 8);
      v.x += b2f(ov.x);
      v.y += b2f(ov.y);
      v.z += b2f(ov.z);
      v.w += b2f(ov.w);
    }
    *(float4*)(out + base + (long)h * 512) = v;
  }
}

// ============================ host launcher =================================
extern "C" void kernel_launch(void* const* d_in, const int* in_sizes, int n_in,
                              void* d_out, int out_size, void* d_ws, size_t ws_size,
                              hipStream_t stream) {
  const float* fm     = (const float*)d_in[0];
  const float* unc    = (const float*)d_in[1];
  const float* nw     = (const float*)d_in[2];
  const float* nb     = (const float*)d_in[3];
  const float* w_lin0 = (const float*)d_in[4];
  const float* b_lin0 = (const float*)d_in[5];
  const float* w_qkv0 = (const float*)d_in[6];
  const float* w_lin1 = (const float*)d_in[7];
  const float* b_lin1 = (const float*)d_in[8];
  const float* w_qkv1 = (const float*)d_in[9];
  const float* w_proj = (const float*)d_in[10];
  const float* b_proj = (const float*)d_in[11];
  float* out = (float*)d_out;

  const int nWF = 1228, totWin = 2456;
  const long totTok = (long)totWin * 64;

  char* p = (char*)d_ws;
  auto alloc = [&](size_t bytes) {
    char* r = p;
    p += (bytes + 255) & ~(size_t)255;
    return r;
  };
  float* scores = (float*)alloc(8192 * 4);
  int* win2row  = (int*)alloc(8192 * 4);
  int* row2win  = (int*)alloc(totWin * 4);
  u16* wT       = (u16*)alloc((size_t)2097152 * 2);
  u16* out_f    = (u16*)alloc((size_t)(totTok + 256) * 256 * 2);
  size_t persist = (size_t)(p - (char*)d_ws);

  // single-chunk preferred (R12 showed multi-chunk L3 blocking is a net loss)
  int wpc = totWin;
  {
    const int cands[6] = {1, 2, 4, 8, 16, 32};
    for (int ci = 0; ci < 6; ++ci) {
      int n = cands[ci];
      int wp = ((totWin + n - 1) / n + 3) & ~3;
      size_t mc = (size_t)wp * 64;
      size_t need = persist + 4096 +
                    ((mc * 256 * 2 + 255) & ~(size_t)255) +
                    2 * ((mc * 512 * 2 + 255) & ~(size_t)255) +
                    ((mc * 1536 * 2 + 255) & ~(size_t)255);
      if (need <= ws_size) { wpc = wp; break; }
    }
  }
  long mcap = (long)wpc * 64;
  u16* xn   = (u16*)alloc((size_t)mcap * 256 * 2);
  u16* xfa  = (u16*)alloc((size_t)mcap * 512 * 2);
  u16* xfb  = (u16*)alloc((size_t)mcap * 512 * 2);
  u16* qkvb = (u16*)alloc((size_t)mcap * 1536 * 2);

  u16* wT_lin0 = wT;
  u16* wT_qkv0 = wT + 131072;
  u16* wT_lin1 = wT + 917504;
  u16* wT_qkv1 = wT + 1179648;
  u16* wT_proj = wT + 1966080;
  k_transpose_w<<<(131072 + 255) / 256, 256, 0, stream>>>(w_lin0, wT_lin0, 256, 512);
  k_transpose_w<<<(786432 + 255) / 256, 256, 0, stream>>>(w_qkv0, wT_qkv0, 512, 1536);
  k_transpose_w<<<(262144 + 255) / 256, 256, 0, stream>>>(w_lin1, wT_lin1, 512, 512);
  k_transpose_w<<<(786432 + 255) / 256, 256, 0, stream>>>(w_qkv1, wT_qkv1, 512, 1536);
  k_transpose_w<<<(131072 + 255) / 256, 256, 0, stream>>>(w_proj, wT_proj, 512, 256);

  k_scores<<<32, 256, 0, stream>>>(unc, scores);
  k_topk<<<2, 1024, 0, stream>>>(scores, row2win, win2row, nWF);

  for (int w0 = 0; w0 < totWin; w0 += wpc) {
    int rem = totWin - w0;
    int wn = (wpc < rem) ? wpc : rem;       // multiple of 4
    int mT = wn / 4;                         // (wn*64)/256
    k_gather_ln<<<wn, 256, 0, stream>>>(fm, nw, nb, row2win, xn, w0);
    k_gemm256<1, 2, 256><<<mT * 2, 512, 0, stream>>>(xn, wT_lin0, b_lin0, nullptr, xfa, 512);
    k_gemm256<4, 6, 512><<<mT * 6, 512, 0, stream>>>(xfa, wT_qkv0, nullptr, nullptr, qkvb, 1536);
    k_attn<<<wn * 8, 256, 0, stream>>>(qkvb, xfa);
    k_gemm256<2, 2, 512><<<mT * 2, 512, 0, stream>>>(xfa, wT_lin1, b_lin1, xfa, xfb, 512);
    k_gemm256<4, 6, 512><<<mT * 6, 512, 0, stream>>>(xfb, wT_qkv1, nullptr, nullptr, qkvb, 1536);
    k_attn<<<wn * 8, 256, 0, stream>>>(qkvb, xfb);
    k_gemm256<3, 1, 512><<<mT * 1, 512, 0, stream>>>(xfb, wT_proj, b_proj, xn,
                                                     out_f + (long)w0 * 16384, 256);
  }
  k_assemble<<<32768, 256, 0, stream>>>(fm, out_f, win2row, out);
}